// Round 13
// baseline (463.572 us; speedup 1.0000x reference)
//
#include <hip/hip_runtime.h>
#include <cstdint>
#include <cstddef>

static const int CNU = 100000;
static const int CNI = 50000;
static const int CD  = 128;
static const int CL  = 2;
static const int CQ  = 5;
static const int CNE = 1000000;
static const int CB  = 4096;
#define INV_TEMP 5.0f
#define LAMBDA1 0.2f
#define KEEP_P 0.8f
#define CAP_R 40
#define CAP_C 56
#define NBU 391            // ceil(100000/256)
#define NBI 196            // ceil(50000/256)
#define NXCD 8
#define SEGCAP_U 512
#define SEGCAP_I 896
#define QSCALE 655280.0f   // 8191/0.0125
#define QSTEP  1.5258902e-6f
#define NCH_I 391          // item chunks (128 rows) -> Tu
#define NCH_U 782          // user chunks (128 rows) -> Ti
#define NCH   (NCH_I+NCH_U)
#define NBF   3907         // binfill blocks = ceil(1e6/256)
#define NCVT  2344         // cvt blocks (grid-stride)
#define NGA   6144         // gacc-init blocks (2 items/block)
#define NSPMM 37500        // (CNU+CNI)/4

typedef unsigned short ushortT;
typedef __attribute__((ext_vector_type(8))) short bf16x8;
typedef __attribute__((ext_vector_type(4))) float f32x4;

// ---------------- threefry2x32 (JAX-compatible, 20 rounds) ----------------
__host__ __device__ inline uint32_t rotl32(uint32_t v, int r){ return (v<<r)|(v>>(32-r)); }

__host__ __device__ inline void threefry2x32(uint32_t k0, uint32_t k1, uint32_t x0, uint32_t x1,
                                             uint32_t* o0, uint32_t* o1){
  uint32_t ks0=k0, ks1=k1, ks2=k0^k1^0x1BD11BDAu;
  x0+=ks0; x1+=ks1;
#define TF_R(r) { x0+=x1; x1=rotl32(x1,(r)); x1^=x0; }
  TF_R(13) TF_R(15) TF_R(26) TF_R(6)   x0+=ks1; x1+=ks2+1u;
  TF_R(17) TF_R(29) TF_R(16) TF_R(24)  x0+=ks2; x1+=ks0+2u;
  TF_R(13) TF_R(15) TF_R(26) TF_R(6)   x0+=ks0; x1+=ks1+3u;
  TF_R(17) TF_R(29) TF_R(16) TF_R(24)  x0+=ks1; x1+=ks2+4u;
  TF_R(13) TF_R(15) TF_R(26) TF_R(6)   x0+=ks2; x1+=ks0+5u;
#undef TF_R
  *o0=x0; *o1=x1;
}

static void split3(uint32_t k0, uint32_t k1, uint32_t o[6]){
  uint32_t a,b;
  threefry2x32(k0,k1,0u,3u,&a,&b); o[0]=a; o[3]=b;
  threefry2x32(k0,k1,1u,4u,&a,&b); o[1]=a; o[4]=b;
  threefry2x32(k0,k1,2u,5u,&a,&b); o[2]=a; o[5]=b;
}

__device__ inline float u01(uint32_t b){
  return __uint_as_float((b>>9)|0x3f800000u) - 1.0f;
}
__device__ inline float lrelu(float x){ return x>0.0f ? x : 0.5f*x; }
__device__ inline uint32_t f2bf(float f){
  uint32_t u = __float_as_uint(f);
  u += 0x7fffu + ((u>>16)&1u);
  return u>>16;
}
__device__ inline float bf2f(ushortT s){
  return __uint_as_float(((uint32_t)s)<<16);
}
__device__ inline float bflo(int x){ return __uint_as_float(((uint32_t)x)<<16); }
__device__ inline float bfhi(int x){ return __uint_as_float(((uint32_t)x)&0xffff0000u); }

__device__ inline int keep_draw(uint32_t k0, uint32_t k1, uint32_t e){
  const uint32_t H = CNE/2;
  uint32_t c0 = (e<H)? e : e-H;
  uint32_t r0,r1;
  threefry2x32(k0,k1,c0,c0+H,&r0,&r1);
  uint32_t rw = (e<H)? r0 : r1;
  return (rw < 3435974144u) ? 1 : 0;   // u01 < 0.8
}

// real XCD id: s_getreg(HW_REG_XCC_ID=20)  [measured: learn_hip m09]
__device__ inline uint32_t xcc_id(){
  return __builtin_amdgcn_s_getreg((3<<11) | (0<<6) | 20) & (NXCD-1);
}

// ---------------- fused setup: binfill || cvt || gacc3-init ----------------
__global__ __launch_bounds__(256) void k_setup(
    const int* __restrict__ rows, const int* __restrict__ cols,
    const float* __restrict__ vals,
    int* __restrict__ bcnt_u, int* __restrict__ bcnt_i,
    int2* __restrict__ bin_u, int2* __restrict__ bin_i,
    const float* __restrict__ Euf, const float* __restrict__ Eif,
    ushortT* __restrict__ Eub, ushortT* __restrict__ Eib,
    const int* __restrict__ uids, const int* __restrict__ pids, const int* __restrict__ nids,
    float* __restrict__ usum, float* __restrict__ iposb, float* __restrict__ inegb,
    uint32_t ka00, uint32_t ka01, uint32_t ka10, uint32_t ka11,
    uint32_t kb00, uint32_t kb01, uint32_t kb10, uint32_t kb11){
  int t = threadIdx.x;
  if(blockIdx.x < NBF){
    // -------- binfill --------
    int e = blockIdx.x*256 + t;
    if(e >= CNE) return;
    int xid = (int)xcc_id();
    int r = rows[e], c = cols[e];
    float v = vals[e] * (1.0f/KEEP_P);
    uint32_t q = (uint32_t)(v*QSCALE + 0.5f);
    if(q > 8191u) q = 8191u;
    uint32_t ue = (uint32_t)e;
    uint32_t d0r = keep_draw(ka00, ka01, ue);
    uint32_t d1r = keep_draw(ka10, ka11, ue);
    uint32_t d0c = keep_draw(kb00, kb01, ue);
    uint32_t d1c = keep_draw(kb10, kb11, ue);
    {
      int seg = (r>>8)*NXCD + xid;
      int slot = atomicAdd(&bcnt_u[seg*16], 1);
      if(slot < SEGCAP_U){
        int2 p; p.x = c | ((r&255)<<17); p.y = (int)((d0r<<14)|(d1r<<13)|q);
        bin_u[(size_t)seg*SEGCAP_U + slot] = p;
      }
    }
    {
      int seg = (c>>8)*NXCD + xid;
      int slot = atomicAdd(&bcnt_i[seg*16], 1);
      if(slot < SEGCAP_I){
        int2 p; p.x = r | ((c&255)<<17); p.y = (int)((d0c<<14)|(d1c<<13)|q);
        bin_i[(size_t)seg*SEGCAP_I + slot] = p;
      }
    }
  } else if(blockIdx.x < NBF+NCVT){
    // -------- fp32 -> bf16 convert (grid-stride) --------
    const size_t nu = (size_t)CNU*CD/8;
    const size_t M4 = (size_t)(CNU+CNI)*CD/8;
    size_t i0 = (size_t)(blockIdx.x - NBF)*256 + t;
    for(size_t i=i0; i<M4; i += (size_t)NCVT*256){
      const float* src; ushortT* dst; size_t j;
      if(i < nu){ src=Euf; dst=Eub; j=i; }
      else{ src=Eif; dst=Eib; j=i-nu; }
      const float4* s = (const float4*)(src + j*8);
      float4 a = s[0], b = s[1];
      int4 o;
      o.x = (int)(f2bf(a.x) | (f2bf(a.y)<<16));
      o.y = (int)(f2bf(a.z) | (f2bf(a.w)<<16));
      o.z = (int)(f2bf(b.x) | (f2bf(b.y)<<16));
      o.w = (int)(f2bf(b.z) | (f2bf(b.w)<<16));
      ((int4*)dst)[j] = o;
    }
  } else {
    // -------- gacc3 init from fp32 originals (2 items/block) --------
    int item = (blockIdx.x - NBF - NCVT)*2 + (t>>7);
    int side = item >> 12;       // 0,1,2
    int b    = item & 4095;
    int d    = t & 127;
    const int* ids = (side==0)? uids : (side==1)? pids : nids;
    const float* E = (side==0)? Euf : Eif;
    float* S = (side==0)? usum : (side==1)? iposb : inegb;
    S[(size_t)b*CD+d] = E[(size_t)ids[b]*CD+d];
  }
}

// Pass B: one WG per bin; read the 8 segments, scatter in LDS, write coalesced.
__global__ __launch_bounds__(256) void k_build(
    const int* __restrict__ bcnt_u, const int2* __restrict__ bin_u,
    const int* __restrict__ bcnt_i, const int2* __restrict__ bin_i,
    int* __restrict__ cnt_u, uint32_t* __restrict__ pad_u,
    int* __restrict__ cnt_i, uint32_t* __restrict__ pad_i){
  __shared__ int rc[256];
  __shared__ uint32_t lpad[256*CAP_C];
  bool user = blockIdx.x < NBU;
  int bin  = user ? blockIdx.x : blockIdx.x - NBU;
  int N    = user ? CNU : CNI;
  int CAP  = user ? CAP_R : CAP_C;
  int scap = user ? SEGCAP_U : SEGCAP_I;
  const int*  bcnt = user ? bcnt_u : bcnt_i;
  const int2* bino = user ? bin_u : bin_i;
  int* cnto = user ? cnt_u : cnt_i;
  uint32_t* pado = user ? pad_u : pad_i;
  int base = bin<<8;
  int nrows = N - base; if(nrows > 256) nrows = 256;
  int t = threadIdx.x;
  rc[t] = 0;
  __syncthreads();
#pragma unroll
  for(int sgi=0; sgi<NXCD; sgi++){
    int seg = bin*NXCD + sgi;
    int cnt = bcnt[seg*16];
    if(cnt > scap) cnt = scap;
    const int2* bins = bino + (size_t)seg*scap;
    for(int i=t; i<cnt; i+=256){
      int2 p = bins[i];
      int local = ((uint32_t)p.x) >> 17;
      uint32_t gi = (uint32_t)p.x & 0x1FFFFu;
      int slot = atomicAdd(&rc[local], 1);
      if(slot < CAP) lpad[local*CAP + slot] = (gi<<15) | (uint32_t)p.y;
    }
  }
  __syncthreads();
  if(t < nrows){ int n = rc[t]; cnto[base+t] = n>CAP ? CAP : n; }
  int tot4 = (nrows*CAP) >> 2;
  int4* dst = (int4*)(pado + (size_t)base*CAP);
  const int4* src = (const int4*)lpad;
  for(int i4=t; i4<tot4; i4+=256) dst[i4] = src[i4];
}

// ---------------- per-layer kernels (standalone: occupancy matters) ----------------

// bf16 spmm over padded buckets: one wave/dest row, 16 lanes/edge, 4 edge streams,
// LDS meta broadcast, fused E_new = E_old + act(Z)
__global__ __launch_bounds__(256) void k_spmm(
    const int* __restrict__ cnt_u, const uint32_t* __restrict__ pad_u,
    const int* __restrict__ cnt_i, const uint32_t* __restrict__ pad_i,
    const ushortT* __restrict__ Eu_in, const ushortT* __restrict__ Ei_in,
    ushortT* __restrict__ Eu_out, ushortT* __restrict__ Ei_out, int layer){
  __shared__ int2 meta[4][64];
  int wid = threadIdx.x>>6;
  int w = blockIdx.x*4 + wid;
  if(w >= CNU+CNI) return;
  int lane = threadIdx.x & 63;
  bool user = (w < CNU);
  const int*      cnt = user ? cnt_u : cnt_i;
  const uint32_t* pad = user ? pad_u : pad_i;
  int cap             = user ? CAP_R : CAP_C;
  const ushortT* X    = user ? Ei_in : Eu_in;
  const ushortT* Ein  = user ? Eu_in : Ei_in;
  ushortT* Eout       = user ? Eu_out : Ei_out;
  int row = user ? w : (w - CNU);
  int n = cnt[row]; if(n > cap) n = cap;
  const uint32_t* base = pad + (size_t)row*cap;
  int s = lane>>4, l16 = lane&15;

  int2 mm = make_int2(0,0);
  if(lane < n){
    uint32_t mw = base[lane];
    uint32_t keep = (mw >> (14-layer)) & 1u;
    float vv = keep ? (float)(mw & 0x1FFFu) * QSTEP : 0.0f;
    mm.x = (int)(mw >> 15);
    mm.y = __float_as_int(vv);
  }
  meta[wid][lane] = mm;

  float acc[8];
#pragma unroll
  for(int k=0;k<8;k++) acc[k]=0.0f;
  int np = (n+3)>>2;
  for(int i=0;i<np;i++){
    int2 md = meta[wid][i*4+s];
    float vv = __int_as_float(md.y);
    if(vv != 0.0f){
      int4 xv = *(const int4*)(X + (size_t)md.x*CD + l16*8);
      acc[0] += vv*bflo(xv.x); acc[1] += vv*bfhi(xv.x);
      acc[2] += vv*bflo(xv.y); acc[3] += vv*bfhi(xv.y);
      acc[4] += vv*bflo(xv.z); acc[5] += vv*bfhi(xv.z);
      acc[6] += vv*bflo(xv.w); acc[7] += vv*bfhi(xv.w);
    }
  }
#pragma unroll
  for(int k=0;k<8;k++){
    acc[k] += __shfl_xor(acc[k], 16);
    acc[k] += __shfl_xor(acc[k], 32);
  }
  if(s==0){
    int4 ev = *(const int4*)(Ein + (size_t)row*CD + l16*8);
    int4 o;
    o.x = (int)(f2bf(bflo(ev.x)+lrelu(acc[0])) | (f2bf(bfhi(ev.x)+lrelu(acc[1]))<<16));
    o.y = (int)(f2bf(bflo(ev.y)+lrelu(acc[2])) | (f2bf(bfhi(ev.y)+lrelu(acc[3]))<<16));
    o.z = (int)(f2bf(bflo(ev.z)+lrelu(acc[4])) | (f2bf(bfhi(ev.z)+lrelu(acc[5]))<<16));
    o.w = (int)(f2bf(bflo(ev.w)+lrelu(acc[6])) | (f2bf(bfhi(ev.w)+lrelu(acc[7]))<<16));
    *(int4*)(Eout + (size_t)row*CD + l16*8) = o;
  }
}

// latency-optimized T build: one block per 128-row chunk; int4 loads; shfl+LDS reduce.
__global__ __launch_bounds__(256) void k_vtE2(const float* __restrict__ vt, const float* __restrict__ ut,
                       const ushortT* __restrict__ Ei, const ushortT* __restrict__ Eu,
                       float* __restrict__ Tbuf, int layer){
  bool sideU = blockIdx.x >= NCH_I;
  int chunk = sideU ? (blockIdx.x - NCH_I) : blockIdx.x;
  const float* M   = sideU ? ut : vt;
  const ushortT* X = sideU ? Eu : Ei;
  float* T         = Tbuf + layer*(2*CQ*128) + (sideU?1:0)*(CQ*128);
  int N            = sideU ? CNU : CNI;
  int base = chunk*128;
  int t = threadIdx.x;
  int rg = t>>4, dg = t&15;
  float acc[CQ][8];
#pragma unroll
  for(int q=0;q<CQ;q++)
#pragma unroll
    for(int j=0;j<8;j++) acc[q][j]=0.0f;
  for(int rr=rg; rr<128; rr+=16){
    int r = base+rr;
    if(r >= N) break;
    int4 xv = ((const int4*)(X + (size_t)r*CD))[dg];
    float x[8];
    x[0]=bflo(xv.x); x[1]=bfhi(xv.x); x[2]=bflo(xv.y); x[3]=bfhi(xv.y);
    x[4]=bflo(xv.z); x[5]=bfhi(xv.z); x[6]=bflo(xv.w); x[7]=bfhi(xv.w);
#pragma unroll
    for(int q=0;q<CQ;q++){
      float m = M[(size_t)q*N + r];
#pragma unroll
      for(int j=0;j<8;j++) acc[q][j] += m*x[j];
    }
  }
#pragma unroll
  for(int q=0;q<CQ;q++)
#pragma unroll
    for(int j=0;j<8;j++){
      float v = acc[q][j];
      v += __shfl_xor(v, 16);
      v += __shfl_xor(v, 32);
      acc[q][j] = v;
    }
  __shared__ float red[4][656];   // stride 41 per dg to avoid bank conflicts
  int wv = t>>6;
  int lane = t&63;
  if(lane < 16){
#pragma unroll
    for(int q=0;q<CQ;q++)
#pragma unroll
      for(int j=0;j<8;j++)
        red[wv][dg*41 + q*8 + j] = acc[q][j];
  }
  __syncthreads();
  for(int i=t; i<CQ*128; i+=256){
    int q = i>>7, rem = i&127;
    int dgi = rem>>3, j = rem&7;
    int idx = dgi*41 + q*8 + j;
    float s = red[0][idx] + red[1][idx] + red[2][idx] + red[3][idx];
    atomicAdd(&T[i], s);
  }
}

// ---------------- fused per-layer sampled: hyper | gnn | gacc ----------------
__global__ __launch_bounds__(128) void k_sampled(
    const int* __restrict__ uids, const int* __restrict__ iids,
    const int* __restrict__ pids, const int* __restrict__ nids,
    const float* __restrict__ u_mul_s, const float* __restrict__ v_mul_s,
    const float* __restrict__ Tbuf, const float* __restrict__ W,
    const ushortT* __restrict__ EuN, const ushortT* __restrict__ EuO,
    const ushortT* __restrict__ EiN, const ushortT* __restrict__ EiO,
    ushortT* __restrict__ hu, ushortT* __restrict__ hi,
    ushortT* __restrict__ gu, ushortT* __restrict__ gi,
    float* __restrict__ usum, float* __restrict__ iposb, float* __restrict__ inegb,
    int layer){
  __shared__ float red[128];
  __shared__ float gn[128];
  int item = blockIdx.x;
  int d = threadIdx.x;
  if(item < 2*CB){
    // hyper
    int side = item >> 12;
    int b    = item & 4095;
    const int* ids = side ? iids : uids;
    const float* ms = side ? v_mul_s : u_mul_s;
    const float* T  = Tbuf + layer*(2*CQ*128) + side*(CQ*128);
    ushortT* outp = side ? hi : hu;
    int id = ids[b];
    float g = 0.0f;
#pragma unroll
    for(int q=0;q<CQ;q++) g += ms[(size_t)id*CQ+q]*T[q*128+d];
    g = lrelu(g);
    red[d]=g*g; __syncthreads();
    for(int s=64;s>0;s>>=1){ if(d<s) red[d]+=red[d+s]; __syncthreads(); }
    float nrm = sqrtf(red[0]);
    gn[d] = g / fmaxf(nrm, 1e-12f);
    __syncthreads();
    float h=0.0f;
    for(int k=0;k<128;k++) h += gn[k]*W[k*128+d];
    outp[(size_t)b*128+d]=(ushortT)f2bf(h);
  } else if(item < 4*CB){
    // gnn
    int j = item - 2*CB;
    int side = j >> 12;
    int b    = j & 4095;
    const int* ids = side ? iids : uids;
    const ushortT* En = side ? EiN : EuN;
    const ushortT* Eo = side ? EiO : EuO;
    ushortT* outp = side ? gi : gu;
    int id = ids[b];
    float z = bf2f(En[(size_t)id*CD+d]) - bf2f(Eo[(size_t)id*CD+d]);
    red[d]=z*z; __syncthreads();
    for(int s=64;s>0;s>>=1){ if(d<s) red[d]+=red[d+s]; __syncthreads(); }
    outp[(size_t)b*CD+d] = (ushortT)f2bf(z / fmaxf(sqrtf(red[0]), 1e-12f));
  } else {
    // gacc accumulate
    int j = item - 4*CB;
    int side = j >> 12;   // 0,1,2
    int b    = j & 4095;
    const int* ids = (side==0)? uids : (side==1)? pids : nids;
    const ushortT* E = (side==0)? EuN : EiN;
    float* S = (side==0)? usum : (side==1)? iposb : inegb;
    S[(size_t)b*CD+d] += bf2f(E[(size_t)ids[b]*CD+d]);
  }
}

// MFMA NCE with LDS-staged, XOR-swizzled B tiles (shared by all 4 waves).
// grid (rowblocks=16, colchunks=8, combos=4); 64 rows/wave; atomic partial rowsums.
__global__ __launch_bounds__(256) void k_nce_mfma(const ushortT* __restrict__ gnnb,
                                                  const ushortT* __restrict__ hypb,
                                                  float* __restrict__ neg){
  __shared__ char bs[64*256];   // 64 cols(H-rows) x 128 bf16, swizzled
  int c = blockIdx.z;
  const ushortT* G = gnnb + (size_t)c*CB*CD;
  const ushortT* H = hypb + (size_t)c*CB*CD;
  int wid  = threadIdx.x >> 6;
  int lane = threadIdx.x & 63;
  int lr = lane & 15;
  int lk = lane >> 4;
  int rb = blockIdx.x*256 + wid*64;
  int cc = blockIdx.y*512;
  int t = threadIdx.x;

  bf16x8 a[4][4];
#pragma unroll
  for(int rt=0;rt<4;rt++)
#pragma unroll
    for(int ks=0;ks<4;ks++)
      a[rt][ks] = *(const bf16x8*)(G + (size_t)(rb+rt*16+lr)*CD + ks*32 + lk*8);

  float rsum[4][4];
#pragma unroll
  for(int rt=0;rt<4;rt++)
#pragma unroll
    for(int r=0;r<4;r++) rsum[rt][r]=0.0f;

  int str = t>>4, scg = t&15;              // staging row / 16B-colgroup
  for(int cb64 = cc; cb64 < cc+512; cb64 += 64){
    __syncthreads();                       // protect previous tile reads
#pragma unroll
    for(int it=0; it<4; it++){
      int r = str + it*16;                 // 0..63
      int byte = r*256 + ((scg*16) ^ ((r&7)<<4));
      *(int4*)(bs + byte) = *(const int4*)(H + (size_t)(cb64 + r)*CD + scg*8);
    }
    __syncthreads();
#pragma unroll
    for(int s16=0; s16<4; s16++){
      int row = s16*16 + lr;
      bf16x8 b[4];
#pragma unroll
      for(int ks=0; ks<4; ks++){
        int byte = row*256 + ((ks*64 + lk*16) ^ ((row&7)<<4));
        b[ks] = *(const bf16x8*)(bs + byte);
      }
#pragma unroll
      for(int rt=0;rt<4;rt++){
        f32x4 acc = {0.f,0.f,0.f,0.f};
#pragma unroll
        for(int ks=0;ks<4;ks++)
          acc = __builtin_amdgcn_mfma_f32_16x16x32_bf16(a[rt][ks], b[ks], acc, 0,0,0);
#pragma unroll
        for(int r=0;r<4;r++)
          rsum[rt][r] += __expf(acc[r]*INV_TEMP);
      }
    }
  }
#pragma unroll
  for(int rt=0;rt<4;rt++)
#pragma unroll
    for(int r=0;r<4;r++){
      float s = rsum[rt][r];
      s += __shfl_xor(s, 1);
      s += __shfl_xor(s, 2);
      s += __shfl_xor(s, 4);
      s += __shfl_xor(s, 8);
      if(lr==0) atomicAdd(&neg[(size_t)c*CB + rb + rt*16 + lk*4 + r], s);
    }
}

// ---------------- fused tail: loss || bpr ----------------
__global__ __launch_bounds__(256) void k_tail(
    const ushortT* __restrict__ gnnb, const ushortT* __restrict__ hypb,
    const float* __restrict__ neg,
    const float* __restrict__ usum, const float* __restrict__ ipos,
    const float* __restrict__ ineg,
    float* __restrict__ vbuf, float* __restrict__ rbuf,
    uint32_t k0a,uint32_t k0b,uint32_t k1a,uint32_t k1b,
    uint32_t k2a,uint32_t k2b,uint32_t k3a,uint32_t k3b){
  int t = threadIdx.x;
  if(blockIdx.x < 4*CB/4){
    int idx = blockIdx.x*4 + (t>>6);
    int lane = t & 63;
    const ushortT* g = gnnb + (size_t)idx*CD + lane*2;
    const ushortT* h = hypb + (size_t)idx*CD + lane*2;
    float s = bf2f(g[0])*bf2f(h[0]) + bf2f(g[1])*bf2f(h[1]);
#pragma unroll
    for(int m=32; m; m>>=1) s += __shfl_xor(s, m);
    if(lane==0){
      int c = idx>>12, j = idx&4095;
      uint32_t ka = (c==0)?k0a:(c==1)?k1a:(c==2)?k2a:k3a;
      uint32_t kb = (c==0)?k0b:(c==1)?k1b:(c==2)?k2b:k3b;
      uint32_t jj = (j<2048)? (uint32_t)j : (uint32_t)(j-2048);
      uint32_t r0,r1;
      threefry2x32(ka,kb,jj,jj+2048u,&r0,&r1);
      uint32_t rw = (j<2048)? r0 : r1;
      float mask = (u01(rw) > 0.5f) ? 1.0f : 0.0f;
      float p = __expf(s*INV_TEMP);
      vbuf[idx] = -logf(p/(neg[idx]+1e-8f)+1e-8f) * mask;
    }
  } else {
    int bb = blockIdx.x - 4*CB/4;
    int lane = t & 63, sub = t >> 6;
    int b = bb*4 + sub;
    float2 u  = ((const float2*)(usum + (size_t)b*CD))[lane];
    float2 p  = ((const float2*)(ipos + (size_t)b*CD))[lane];
    float2 nn = ((const float2*)(ineg + (size_t)b*CD))[lane];
    float ps = u.x*p.x + u.y*p.y;
    float ns = u.x*nn.x + u.y*nn.y;
    for(int off=32; off; off>>=1){ ps += __shfl_down(ps,off); ns += __shfl_down(ns,off); }
    if(lane==0){
      float v = 1.0f - ps + ns;
      rbuf[b] = v>0.0f ? v : 0.0f;
    }
  }
}

__global__ void k_final(const float* __restrict__ vbuf, const float* __restrict__ rbuf,
                        float* __restrict__ out){
  int t = threadIdx.x;
  float s=0.0f, r=0.0f;
  for(int i=t; i<4*CB; i+=256) s += vbuf[i];
  for(int i=t; i<CB;   i+=256) r += rbuf[i];
  __shared__ float rs[256], rr[256];
  rs[t]=s; rr[t]=r; __syncthreads();
  for(int o=128;o>0;o>>=1){ if(t<o){ rs[t]+=rs[t+o]; rr[t]+=rr[t+o]; } __syncthreads(); }
  if(t==0){
    float loss_s = rs[0];
    float loss_r = rr[0]/(float)CB;
    out[0] = loss_r + LAMBDA1*loss_s;
    out[1] = loss_r;
    out[2] = loss_s;
  }
}

// ---------------- launch ----------------
extern "C" void kernel_launch(void* const* d_in, const int* in_sizes, int n_in,
                              void* d_out, int out_size, void* d_ws, size_t ws_size,
                              hipStream_t stream){
  const float* E_u_0   = (const float*)d_in[0];
  const float* E_i_0   = (const float*)d_in[1];
  const float* W_s     = (const float*)d_in[2];
  const float* u_mul_s = (const float*)d_in[3];
  const float* v_mul_s = (const float*)d_in[4];
  const float* ut      = (const float*)d_in[5];
  const float* vt      = (const float*)d_in[6];
  const float* adj_vals= (const float*)d_in[7];
  const int*   adj_rows= (const int*)d_in[8];
  const int*   adj_cols= (const int*)d_in[9];
  const int*   uids    = (const int*)d_in[10];
  const int*   iids    = (const int*)d_in[11];
  const int*   pos_ids = (const int*)d_in[12];
  const int*   neg_ids = (const int*)d_in[13];
  float* out = (float*)d_out;

  float* ws = (float*)d_ws;
  size_t off = 0;
  auto alloc = [&](size_t n){ float* p = ws + off; off += (n+3)&~(size_t)3; return p; };
  ushortT* Eu0b = (ushortT*)alloc((size_t)CNU*CD/2);
  ushortT* Ei0b = (ushortT*)alloc((size_t)CNI*CD/2);
  ushortT* EuA  = (ushortT*)alloc((size_t)CNU*CD/2);
  ushortT* EuB  = (ushortT*)alloc((size_t)CNU*CD/2);
  ushortT* EiA  = (ushortT*)alloc((size_t)CNI*CD/2);
  ushortT* EiB  = (ushortT*)alloc((size_t)CNI*CD/2);
  float* Tbuf = alloc(2*2*CQ*128);          // [layer][side][640]
  float* negb = alloc(4*CB);                // adjacent to Tbuf -> single memset
  ushortT* gnnb = (ushortT*)alloc(4*(size_t)CB*CD/2);
  ushortT* hypb = (ushortT*)alloc(4*(size_t)CB*CD/2);
  float* usum = alloc((size_t)CB*CD);
  float* iposb= alloc((size_t)CB*CD);
  float* inegb= alloc((size_t)CB*CD);
  float* vbuf = alloc(4*CB);
  float* rbuf = alloc(CB);
  int* bcnt_u = (int*)alloc((size_t)NBU*NXCD*16);
  int* bcnt_i = (int*)alloc((size_t)NBI*NXCD*16);   // adjacent to bcnt_u
  int2* bin_u = (int2*)alloc((size_t)NBU*NXCD*SEGCAP_U*2);
  int2* bin_i = (int2*)alloc((size_t)NBI*NXCD*SEGCAP_I*2);
  int* cnt_u = (int*)alloc(CNU);
  int* cnt_i = (int*)alloc(CNI);
  uint32_t* pad_u = (uint32_t*)alloc((size_t)CNU*CAP_R);
  uint32_t* pad_i = (uint32_t*)alloc((size_t)CNI*CAP_C);

  uint32_t rk0 = 0u, rk1 = 42u;
  uint32_t kd[CL][2][2];
  uint32_t km[4][2];
  for(int l=0;l<CL;l++){
    uint32_t o[6]; split3(rk0,rk1,o);
    kd[l][0][0]=o[0]; kd[l][0][1]=o[1];
    kd[l][1][0]=o[2]; kd[l][1][1]=o[3];
    rk0=o[4]; rk1=o[5];
  }
  for(int l=0;l<CL;l++){
    uint32_t o[6]; split3(rk0,rk1,o);
    km[l*2+0][0]=o[0]; km[l*2+0][1]=o[1];
    km[l*2+1][0]=o[2]; km[l*2+1][1]=o[3];
    rk0=o[4]; rk1=o[5];
  }

  // two fused memsets (adjacent allocations)
  hipMemsetAsync(bcnt_u, 0, ((size_t)NBU+NBI)*NXCD*16*sizeof(int), stream);
  hipMemsetAsync(Tbuf, 0, (2*2*CQ*128 + 4*CB)*sizeof(float), stream);

  // D1: binfill || cvt || gacc-init
  k_setup<<<NBF+NCVT+NGA,256,0,stream>>>(adj_rows, adj_cols, adj_vals,
      bcnt_u, bcnt_i, bin_u, bin_i,
      E_u_0, E_i_0, Eu0b, Ei0b,
      uids, pos_ids, neg_ids, usum, iposb, inegb,
      kd[0][0][0],kd[0][0][1], kd[1][0][0],kd[1][0][1],
      kd[0][1][0],kd[0][1][1], kd[1][1][0],kd[1][1][1]);

  // D2: bucket build
  k_build<<<NBU+NBI,256,0,stream>>>(bcnt_u, bin_u, bcnt_i, bin_i,
      cnt_u, pad_u, cnt_i, pad_i);

  const ushortT* Eu_cur = Eu0b;
  const ushortT* Ei_cur = Ei0b;
  ushortT* Eu_next_bufs[2] = {EuA, EuB};
  ushortT* Ei_next_bufs[2] = {EiA, EiB};

  for(int l=0;l<CL;l++){
    ushortT* Eu_next = Eu_next_bufs[l];
    ushortT* Ei_next = Ei_next_bufs[l];

    // spmm (occupancy-critical, standalone)
    k_spmm<<<NSPMM,256,0,stream>>>(
        cnt_u, pad_u, cnt_i, pad_i,
        Eu_cur, Ei_cur, Eu_next, Ei_next, l);

    // low-rank projection (standalone)
    k_vtE2<<<NCH,256,0,stream>>>(vt, ut, Ei_cur, Eu_cur, Tbuf, l);

    // hyper | gnn | gacc
    const float* Wl = W_s + (size_t)l*CD*CD;
    k_sampled<<<7*CB,128,0,stream>>>(
        uids, iids, pos_ids, neg_ids, u_mul_s, v_mul_s, Tbuf, Wl,
        Eu_next, Eu_cur, Ei_next, Ei_cur,
        hypb + (size_t)(l*2+0)*CB*CD, hypb + (size_t)(l*2+1)*CB*CD,
        gnnb + (size_t)(l*2+0)*CB*CD, gnnb + (size_t)(l*2+1)*CB*CD,
        usum, iposb, inegb, l);

    Eu_cur = Eu_next; Ei_cur = Ei_next;
  }

  // MFMA NCE
  dim3 gnce(CB/256, CB/512, 4);
  k_nce_mfma<<<gnce,256,0,stream>>>(gnnb, hypb, negb);

  // loss || bpr
  k_tail<<<4*CB/4 + CB/4,256,0,stream>>>(gnnb, hypb, negb,
      usum, iposb, inegb, vbuf, rbuf,
      km[0][0],km[0][1], km[1][0],km[1][1], km[2][0],km[2][1], km[3][0],km[3][1]);

  // final reduce
  k_final<<<1,256,0,stream>>>(vbuf, rbuf, out);
}

// Round 14
// 446.096 us; speedup vs baseline: 1.0392x; 1.0392x over previous
//
#include <hip/hip_runtime.h>
#include <cstdint>
#include <cstddef>

static const int CNU = 100000;
static const int CNI = 50000;
static const int CD  = 128;
static const int CL  = 2;
static const int CQ  = 5;
static const int CNE = 1000000;
static const int CB  = 4096;
#define INV_TEMP 5.0f
#define LAMBDA1 0.2f
#define KEEP_P 0.8f
#define CAP_R 40
#define CAP_C 56
#define NBU 391            // ceil(100000/256)
#define NBI 196            // ceil(50000/256)
#define NXCD 8
#define SEGCAP_U 512
#define SEGCAP_I 896
#define QSCALE 655280.0f   // 8191/0.0125
#define QSTEP  1.5258902e-6f
#define NCH_I 196          // item chunks (256 rows) -> Tu
#define NCH_U 391          // user chunks (256 rows) -> Ti
#define NCH   (NCH_I+NCH_U)
#define NBF   3907         // binfill blocks = ceil(1e6/256)
#define NCVT  2344         // cvt blocks (grid-stride)
#define NGA   6144         // gacc-init blocks (2 items/block)
#define NSPMM 37500        // (CNU+CNI)/4

typedef unsigned short ushortT;
typedef __attribute__((ext_vector_type(8))) short bf16x8;
typedef __attribute__((ext_vector_type(4))) float f32x4;

// ---------------- threefry2x32 (JAX-compatible, 20 rounds) ----------------
__host__ __device__ inline uint32_t rotl32(uint32_t v, int r){ return (v<<r)|(v>>(32-r)); }

__host__ __device__ inline void threefry2x32(uint32_t k0, uint32_t k1, uint32_t x0, uint32_t x1,
                                             uint32_t* o0, uint32_t* o1){
  uint32_t ks0=k0, ks1=k1, ks2=k0^k1^0x1BD11BDAu;
  x0+=ks0; x1+=ks1;
#define TF_R(r) { x0+=x1; x1=rotl32(x1,(r)); x1^=x0; }
  TF_R(13) TF_R(15) TF_R(26) TF_R(6)   x0+=ks1; x1+=ks2+1u;
  TF_R(17) TF_R(29) TF_R(16) TF_R(24)  x0+=ks2; x1+=ks0+2u;
  TF_R(13) TF_R(15) TF_R(26) TF_R(6)   x0+=ks0; x1+=ks1+3u;
  TF_R(17) TF_R(29) TF_R(16) TF_R(24)  x0+=ks1; x1+=ks2+4u;
  TF_R(13) TF_R(15) TF_R(26) TF_R(6)   x0+=ks2; x1+=ks0+5u;
#undef TF_R
  *o0=x0; *o1=x1;
}

static void split3(uint32_t k0, uint32_t k1, uint32_t o[6]){
  uint32_t a,b;
  threefry2x32(k0,k1,0u,3u,&a,&b); o[0]=a; o[3]=b;
  threefry2x32(k0,k1,1u,4u,&a,&b); o[1]=a; o[4]=b;
  threefry2x32(k0,k1,2u,5u,&a,&b); o[2]=a; o[5]=b;
}

__device__ inline float u01(uint32_t b){
  return __uint_as_float((b>>9)|0x3f800000u) - 1.0f;
}
__device__ inline float lrelu(float x){ return x>0.0f ? x : 0.5f*x; }
__device__ inline uint32_t f2bf(float f){
  uint32_t u = __float_as_uint(f);
  u += 0x7fffu + ((u>>16)&1u);
  return u>>16;
}
__device__ inline float bf2f(ushortT s){
  return __uint_as_float(((uint32_t)s)<<16);
}
__device__ inline float bflo(int x){ return __uint_as_float(((uint32_t)x)<<16); }
__device__ inline float bfhi(int x){ return __uint_as_float(((uint32_t)x)&0xffff0000u); }

__device__ inline int keep_draw(uint32_t k0, uint32_t k1, uint32_t e){
  const uint32_t H = CNE/2;
  uint32_t c0 = (e<H)? e : e-H;
  uint32_t r0,r1;
  threefry2x32(k0,k1,c0,c0+H,&r0,&r1);
  uint32_t rw = (e<H)? r0 : r1;
  return (rw < 3435974144u) ? 1 : 0;   // u01 < 0.8
}

// real XCD id: s_getreg(HW_REG_XCC_ID=20)  [measured: learn_hip m09]
__device__ inline uint32_t xcc_id(){
  return __builtin_amdgcn_s_getreg((3<<11) | (0<<6) | 20) & (NXCD-1);
}

// ---------------- fused setup: binfill || cvt || gacc3-init ----------------
__global__ __launch_bounds__(256) void k_setup(
    const int* __restrict__ rows, const int* __restrict__ cols,
    const float* __restrict__ vals,
    int* __restrict__ bcnt_u, int* __restrict__ bcnt_i,
    int2* __restrict__ bin_u, int2* __restrict__ bin_i,
    const float* __restrict__ Euf, const float* __restrict__ Eif,
    ushortT* __restrict__ Eub, ushortT* __restrict__ Eib,
    const int* __restrict__ uids, const int* __restrict__ pids, const int* __restrict__ nids,
    float* __restrict__ usum, float* __restrict__ iposb, float* __restrict__ inegb,
    uint32_t ka00, uint32_t ka01, uint32_t ka10, uint32_t ka11,
    uint32_t kb00, uint32_t kb01, uint32_t kb10, uint32_t kb11){
  int t = threadIdx.x;
  if(blockIdx.x < NBF){
    // -------- binfill --------
    int e = blockIdx.x*256 + t;
    if(e >= CNE) return;
    int xid = (int)xcc_id();
    int r = rows[e], c = cols[e];
    float v = vals[e] * (1.0f/KEEP_P);
    uint32_t q = (uint32_t)(v*QSCALE + 0.5f);
    if(q > 8191u) q = 8191u;
    uint32_t ue = (uint32_t)e;
    uint32_t d0r = keep_draw(ka00, ka01, ue);
    uint32_t d1r = keep_draw(ka10, ka11, ue);
    uint32_t d0c = keep_draw(kb00, kb01, ue);
    uint32_t d1c = keep_draw(kb10, kb11, ue);
    {
      int seg = (r>>8)*NXCD + xid;
      int slot = atomicAdd(&bcnt_u[seg*16], 1);
      if(slot < SEGCAP_U){
        int2 p; p.x = c | ((r&255)<<17); p.y = (int)((d0r<<14)|(d1r<<13)|q);
        bin_u[(size_t)seg*SEGCAP_U + slot] = p;
      }
    }
    {
      int seg = (c>>8)*NXCD + xid;
      int slot = atomicAdd(&bcnt_i[seg*16], 1);
      if(slot < SEGCAP_I){
        int2 p; p.x = r | ((c&255)<<17); p.y = (int)((d0c<<14)|(d1c<<13)|q);
        bin_i[(size_t)seg*SEGCAP_I + slot] = p;
      }
    }
  } else if(blockIdx.x < NBF+NCVT){
    // -------- fp32 -> bf16 convert (grid-stride) --------
    const size_t nu = (size_t)CNU*CD/8;
    const size_t M4 = (size_t)(CNU+CNI)*CD/8;
    size_t i0 = (size_t)(blockIdx.x - NBF)*256 + t;
    for(size_t i=i0; i<M4; i += (size_t)NCVT*256){
      const float* src; ushortT* dst; size_t j;
      if(i < nu){ src=Euf; dst=Eub; j=i; }
      else{ src=Eif; dst=Eib; j=i-nu; }
      const float4* s = (const float4*)(src + j*8);
      float4 a = s[0], b = s[1];
      int4 o;
      o.x = (int)(f2bf(a.x) | (f2bf(a.y)<<16));
      o.y = (int)(f2bf(a.z) | (f2bf(a.w)<<16));
      o.z = (int)(f2bf(b.x) | (f2bf(b.y)<<16));
      o.w = (int)(f2bf(b.z) | (f2bf(b.w)<<16));
      ((int4*)dst)[j] = o;
    }
  } else {
    // -------- gacc3 init from fp32 originals (2 items/block) --------
    int item = (blockIdx.x - NBF - NCVT)*2 + (t>>7);
    int side = item >> 12;       // 0,1,2
    int b    = item & 4095;
    int d    = t & 127;
    const int* ids = (side==0)? uids : (side==1)? pids : nids;
    const float* E = (side==0)? Euf : Eif;
    float* S = (side==0)? usum : (side==1)? iposb : inegb;
    S[(size_t)b*CD+d] = E[(size_t)ids[b]*CD+d];
  }
}

// Pass B: one WG per bin; read the 8 segments, scatter in LDS, write coalesced.
__global__ __launch_bounds__(256) void k_build(
    const int* __restrict__ bcnt_u, const int2* __restrict__ bin_u,
    const int* __restrict__ bcnt_i, const int2* __restrict__ bin_i,
    int* __restrict__ cnt_u, uint32_t* __restrict__ pad_u,
    int* __restrict__ cnt_i, uint32_t* __restrict__ pad_i){
  __shared__ int rc[256];
  __shared__ uint32_t lpad[256*CAP_C];
  bool user = blockIdx.x < NBU;
  int bin  = user ? blockIdx.x : blockIdx.x - NBU;
  int N    = user ? CNU : CNI;
  int CAP  = user ? CAP_R : CAP_C;
  int scap = user ? SEGCAP_U : SEGCAP_I;
  const int*  bcnt = user ? bcnt_u : bcnt_i;
  const int2* bino = user ? bin_u : bin_i;
  int* cnto = user ? cnt_u : cnt_i;
  uint32_t* pado = user ? pad_u : pad_i;
  int base = bin<<8;
  int nrows = N - base; if(nrows > 256) nrows = 256;
  int t = threadIdx.x;
  rc[t] = 0;
  __syncthreads();
#pragma unroll
  for(int sgi=0; sgi<NXCD; sgi++){
    int seg = bin*NXCD + sgi;
    int cnt = bcnt[seg*16];
    if(cnt > scap) cnt = scap;
    const int2* bins = bino + (size_t)seg*scap;
    for(int i=t; i<cnt; i+=256){
      int2 p = bins[i];
      int local = ((uint32_t)p.x) >> 17;
      uint32_t gi = (uint32_t)p.x & 0x1FFFFu;
      int slot = atomicAdd(&rc[local], 1);
      if(slot < CAP) lpad[local*CAP + slot] = (gi<<15) | (uint32_t)p.y;
    }
  }
  __syncthreads();
  if(t < nrows){ int n = rc[t]; cnto[base+t] = n>CAP ? CAP : n; }
  int tot4 = (nrows*CAP) >> 2;
  int4* dst = (int4*)(pado + (size_t)base*CAP);
  const int4* src = (const int4*)lpad;
  for(int i4=t; i4<tot4; i4+=256) dst[i4] = src[i4];
}

// ---------------- per-layer kernels (standalone: occupancy matters) ----------------

// bf16 spmm over padded buckets: one wave/dest row, 16 lanes/edge, 4 edge streams,
// LDS meta broadcast, fused E_new = E_old + act(Z)
__global__ __launch_bounds__(256) void k_spmm(
    const int* __restrict__ cnt_u, const uint32_t* __restrict__ pad_u,
    const int* __restrict__ cnt_i, const uint32_t* __restrict__ pad_i,
    const ushortT* __restrict__ Eu_in, const ushortT* __restrict__ Ei_in,
    ushortT* __restrict__ Eu_out, ushortT* __restrict__ Ei_out, int layer){
  __shared__ int2 meta[4][64];
  int wid = threadIdx.x>>6;
  int w = blockIdx.x*4 + wid;
  if(w >= CNU+CNI) return;
  int lane = threadIdx.x & 63;
  bool user = (w < CNU);
  const int*      cnt = user ? cnt_u : cnt_i;
  const uint32_t* pad = user ? pad_u : pad_i;
  int cap             = user ? CAP_R : CAP_C;
  const ushortT* X    = user ? Ei_in : Eu_in;
  const ushortT* Ein  = user ? Eu_in : Ei_in;
  ushortT* Eout       = user ? Eu_out : Ei_out;
  int row = user ? w : (w - CNU);
  int n = cnt[row]; if(n > cap) n = cap;
  const uint32_t* base = pad + (size_t)row*cap;
  int s = lane>>4, l16 = lane&15;

  int2 mm = make_int2(0,0);
  if(lane < n){
    uint32_t mw = base[lane];
    uint32_t keep = (mw >> (14-layer)) & 1u;
    float vv = keep ? (float)(mw & 0x1FFFu) * QSTEP : 0.0f;
    mm.x = (int)(mw >> 15);
    mm.y = __float_as_int(vv);
  }
  meta[wid][lane] = mm;

  float acc[8];
#pragma unroll
  for(int k=0;k<8;k++) acc[k]=0.0f;
  int np = (n+3)>>2;
  for(int i=0;i<np;i++){
    int2 md = meta[wid][i*4+s];
    float vv = __int_as_float(md.y);
    if(vv != 0.0f){
      int4 xv = *(const int4*)(X + (size_t)md.x*CD + l16*8);
      acc[0] += vv*bflo(xv.x); acc[1] += vv*bfhi(xv.x);
      acc[2] += vv*bflo(xv.y); acc[3] += vv*bfhi(xv.y);
      acc[4] += vv*bflo(xv.z); acc[5] += vv*bfhi(xv.z);
      acc[6] += vv*bflo(xv.w); acc[7] += vv*bfhi(xv.w);
    }
  }
#pragma unroll
  for(int k=0;k<8;k++){
    acc[k] += __shfl_xor(acc[k], 16);
    acc[k] += __shfl_xor(acc[k], 32);
  }
  if(s==0){
    int4 ev = *(const int4*)(Ein + (size_t)row*CD + l16*8);
    int4 o;
    o.x = (int)(f2bf(bflo(ev.x)+lrelu(acc[0])) | (f2bf(bfhi(ev.x)+lrelu(acc[1]))<<16));
    o.y = (int)(f2bf(bflo(ev.y)+lrelu(acc[2])) | (f2bf(bfhi(ev.y)+lrelu(acc[3]))<<16));
    o.z = (int)(f2bf(bflo(ev.z)+lrelu(acc[4])) | (f2bf(bfhi(ev.z)+lrelu(acc[5]))<<16));
    o.w = (int)(f2bf(bflo(ev.w)+lrelu(acc[6])) | (f2bf(bfhi(ev.w)+lrelu(acc[7]))<<16));
    *(int4*)(Eout + (size_t)row*CD + l16*8) = o;
  }
}

// latency-optimized T build: one block per 256-row chunk; int4 loads; shfl+LDS reduce.
__global__ __launch_bounds__(256) void k_vtE2(const float* __restrict__ vt, const float* __restrict__ ut,
                       const ushortT* __restrict__ Ei, const ushortT* __restrict__ Eu,
                       float* __restrict__ Tbuf, int layer){
  bool sideU = blockIdx.x >= NCH_I;
  int chunk = sideU ? (blockIdx.x - NCH_I) : blockIdx.x;
  const float* M   = sideU ? ut : vt;
  const ushortT* X = sideU ? Eu : Ei;
  float* T         = Tbuf + layer*(2*CQ*128) + (sideU?1:0)*(CQ*128);
  int N            = sideU ? CNU : CNI;
  int base = chunk*256;
  int t = threadIdx.x;
  int rg = t>>4, dg = t&15;
  float acc[CQ][8];
#pragma unroll
  for(int q=0;q<CQ;q++)
#pragma unroll
    for(int j=0;j<8;j++) acc[q][j]=0.0f;
  for(int rr=rg; rr<256; rr+=16){
    int r = base+rr;
    if(r >= N) break;
    int4 xv = ((const int4*)(X + (size_t)r*CD))[dg];
    float x[8];
    x[0]=bflo(xv.x); x[1]=bfhi(xv.x); x[2]=bflo(xv.y); x[3]=bfhi(xv.y);
    x[4]=bflo(xv.z); x[5]=bfhi(xv.z); x[6]=bflo(xv.w); x[7]=bfhi(xv.w);
#pragma unroll
    for(int q=0;q<CQ;q++){
      float m = M[(size_t)q*N + r];
#pragma unroll
      for(int j=0;j<8;j++) acc[q][j] += m*x[j];
    }
  }
#pragma unroll
  for(int q=0;q<CQ;q++)
#pragma unroll
    for(int j=0;j<8;j++){
      float v = acc[q][j];
      v += __shfl_xor(v, 16);
      v += __shfl_xor(v, 32);
      acc[q][j] = v;
    }
  __shared__ float red[4][656];   // stride 41 per dg to avoid bank conflicts
  int wv = t>>6;
  int lane = t&63;
  if(lane < 16){
#pragma unroll
    for(int q=0;q<CQ;q++)
#pragma unroll
      for(int j=0;j<8;j++)
        red[wv][dg*41 + q*8 + j] = acc[q][j];
  }
  __syncthreads();
  for(int i=t; i<CQ*128; i+=256){
    int q = i>>7, rem = i&127;
    int dgi = rem>>3, j = rem&7;
    int idx = dgi*41 + q*8 + j;
    float s = red[0][idx] + red[1][idx] + red[2][idx] + red[3][idx];
    atomicAdd(&T[i], s);
  }
}

// ---------------- fused per-layer sampled: hyper | gnn | gacc ----------------
__global__ __launch_bounds__(128) void k_sampled(
    const int* __restrict__ uids, const int* __restrict__ iids,
    const int* __restrict__ pids, const int* __restrict__ nids,
    const float* __restrict__ u_mul_s, const float* __restrict__ v_mul_s,
    const float* __restrict__ Tbuf, const float* __restrict__ W,
    const ushortT* __restrict__ EuN, const ushortT* __restrict__ EuO,
    const ushortT* __restrict__ EiN, const ushortT* __restrict__ EiO,
    ushortT* __restrict__ hu, ushortT* __restrict__ hi,
    ushortT* __restrict__ gu, ushortT* __restrict__ gi,
    float* __restrict__ usum, float* __restrict__ iposb, float* __restrict__ inegb,
    int layer){
  __shared__ float red[128];
  __shared__ float gn[128];
  int item = blockIdx.x;
  int d = threadIdx.x;
  if(item < 2*CB){
    // hyper
    int side = item >> 12;
    int b    = item & 4095;
    const int* ids = side ? iids : uids;
    const float* ms = side ? v_mul_s : u_mul_s;
    const float* T  = Tbuf + layer*(2*CQ*128) + side*(CQ*128);
    ushortT* outp = side ? hi : hu;
    int id = ids[b];
    float g = 0.0f;
#pragma unroll
    for(int q=0;q<CQ;q++) g += ms[(size_t)id*CQ+q]*T[q*128+d];
    g = lrelu(g);
    red[d]=g*g; __syncthreads();
    for(int s=64;s>0;s>>=1){ if(d<s) red[d]+=red[d+s]; __syncthreads(); }
    float nrm = sqrtf(red[0]);
    gn[d] = g / fmaxf(nrm, 1e-12f);
    __syncthreads();
    float h=0.0f;
    for(int k=0;k<128;k++) h += gn[k]*W[k*128+d];
    outp[(size_t)b*128+d]=(ushortT)f2bf(h);
  } else if(item < 4*CB){
    // gnn
    int j = item - 2*CB;
    int side = j >> 12;
    int b    = j & 4095;
    const int* ids = side ? iids : uids;
    const ushortT* En = side ? EiN : EuN;
    const ushortT* Eo = side ? EiO : EuO;
    ushortT* outp = side ? gi : gu;
    int id = ids[b];
    float z = bf2f(En[(size_t)id*CD+d]) - bf2f(Eo[(size_t)id*CD+d]);
    red[d]=z*z; __syncthreads();
    for(int s=64;s>0;s>>=1){ if(d<s) red[d]+=red[d+s]; __syncthreads(); }
    outp[(size_t)b*CD+d] = (ushortT)f2bf(z / fmaxf(sqrtf(red[0]), 1e-12f));
  } else {
    // gacc accumulate
    int j = item - 4*CB;
    int side = j >> 12;   // 0,1,2
    int b    = j & 4095;
    const int* ids = (side==0)? uids : (side==1)? pids : nids;
    const ushortT* E = (side==0)? EuN : EiN;
    float* S = (side==0)? usum : (side==1)? iposb : inegb;
    S[(size_t)b*CD+d] += bf2f(E[(size_t)ids[b]*CD+d]);
  }
}

// MFMA NCE with LDS-staged, XOR-swizzled B tiles (shared by all 4 waves).
// grid (rowblocks=16, colchunks=8, combos=4); 64 rows/wave; atomic partial rowsums.
__global__ __launch_bounds__(256) void k_nce_mfma(const ushortT* __restrict__ gnnb,
                                                  const ushortT* __restrict__ hypb,
                                                  float* __restrict__ neg){
  __shared__ char bs[64*256];   // 64 cols(H-rows) x 128 bf16, swizzled
  int c = blockIdx.z;
  const ushortT* G = gnnb + (size_t)c*CB*CD;
  const ushortT* H = hypb + (size_t)c*CB*CD;
  int wid  = threadIdx.x >> 6;
  int lane = threadIdx.x & 63;
  int lr = lane & 15;
  int lk = lane >> 4;
  int rb = blockIdx.x*256 + wid*64;
  int cc = blockIdx.y*512;
  int t = threadIdx.x;

  bf16x8 a[4][4];
#pragma unroll
  for(int rt=0;rt<4;rt++)
#pragma unroll
    for(int ks=0;ks<4;ks++)
      a[rt][ks] = *(const bf16x8*)(G + (size_t)(rb+rt*16+lr)*CD + ks*32 + lk*8);

  float rsum[4][4];
#pragma unroll
  for(int rt=0;rt<4;rt++)
#pragma unroll
    for(int r=0;r<4;r++) rsum[rt][r]=0.0f;

  int str = t>>4, scg = t&15;              // staging row / 16B-colgroup
  for(int cb64 = cc; cb64 < cc+512; cb64 += 64){
    __syncthreads();                       // protect previous tile reads
#pragma unroll
    for(int it=0; it<4; it++){
      int r = str + it*16;                 // 0..63
      int byte = r*256 + ((scg*16) ^ ((r&7)<<4));
      *(int4*)(bs + byte) = *(const int4*)(H + (size_t)(cb64 + r)*CD + scg*8);
    }
    __syncthreads();
#pragma unroll
    for(int s16=0; s16<4; s16++){
      int row = s16*16 + lr;
      bf16x8 b[4];
#pragma unroll
      for(int ks=0; ks<4; ks++){
        int byte = row*256 + ((ks*64 + lk*16) ^ ((row&7)<<4));
        b[ks] = *(const bf16x8*)(bs + byte);
      }
#pragma unroll
      for(int rt=0;rt<4;rt++){
        f32x4 acc = {0.f,0.f,0.f,0.f};
#pragma unroll
        for(int ks=0;ks<4;ks++)
          acc = __builtin_amdgcn_mfma_f32_16x16x32_bf16(a[rt][ks], b[ks], acc, 0,0,0);
#pragma unroll
        for(int r=0;r<4;r++)
          rsum[rt][r] += __expf(acc[r]*INV_TEMP);
      }
    }
  }
#pragma unroll
  for(int rt=0;rt<4;rt++)
#pragma unroll
    for(int r=0;r<4;r++){
      float s = rsum[rt][r];
      s += __shfl_xor(s, 1);
      s += __shfl_xor(s, 2);
      s += __shfl_xor(s, 4);
      s += __shfl_xor(s, 8);
      if(lr==0) atomicAdd(&neg[(size_t)c*CB + rb + rt*16 + lk*4 + r], s);
    }
}

// ---------------- fused tail: loss || bpr ----------------
__global__ __launch_bounds__(256) void k_tail(
    const ushortT* __restrict__ gnnb, const ushortT* __restrict__ hypb,
    const float* __restrict__ neg,
    const float* __restrict__ usum, const float* __restrict__ ipos,
    const float* __restrict__ ineg,
    float* __restrict__ vbuf, float* __restrict__ rbuf,
    uint32_t k0a,uint32_t k0b,uint32_t k1a,uint32_t k1b,
    uint32_t k2a,uint32_t k2b,uint32_t k3a,uint32_t k3b){
  int t = threadIdx.x;
  if(blockIdx.x < 4*CB/4){
    int idx = blockIdx.x*4 + (t>>6);
    int lane = t & 63;
    const ushortT* g = gnnb + (size_t)idx*CD + lane*2;
    const ushortT* h = hypb + (size_t)idx*CD + lane*2;
    float s = bf2f(g[0])*bf2f(h[0]) + bf2f(g[1])*bf2f(h[1]);
#pragma unroll
    for(int m=32; m; m>>=1) s += __shfl_xor(s, m);
    if(lane==0){
      int c = idx>>12, j = idx&4095;
      uint32_t ka = (c==0)?k0a:(c==1)?k1a:(c==2)?k2a:k3a;
      uint32_t kb = (c==0)?k0b:(c==1)?k1b:(c==2)?k2b:k3b;
      uint32_t jj = (j<2048)? (uint32_t)j : (uint32_t)(j-2048);
      uint32_t r0,r1;
      threefry2x32(ka,kb,jj,jj+2048u,&r0,&r1);
      uint32_t rw = (j<2048)? r0 : r1;
      float mask = (u01(rw) > 0.5f) ? 1.0f : 0.0f;
      float p = __expf(s*INV_TEMP);
      vbuf[idx] = -logf(p/(neg[idx]+1e-8f)+1e-8f) * mask;
    }
  } else {
    int bb = blockIdx.x - 4*CB/4;
    int lane = t & 63, sub = t >> 6;
    int b = bb*4 + sub;
    float2 u  = ((const float2*)(usum + (size_t)b*CD))[lane];
    float2 p  = ((const float2*)(ipos + (size_t)b*CD))[lane];
    float2 nn = ((const float2*)(ineg + (size_t)b*CD))[lane];
    float ps = u.x*p.x + u.y*p.y;
    float ns = u.x*nn.x + u.y*nn.y;
    for(int off=32; off; off>>=1){ ps += __shfl_down(ps,off); ns += __shfl_down(ns,off); }
    if(lane==0){
      float v = 1.0f - ps + ns;
      rbuf[b] = v>0.0f ? v : 0.0f;
    }
  }
}

__global__ void k_final(const float* __restrict__ vbuf, const float* __restrict__ rbuf,
                        float* __restrict__ out){
  int t = threadIdx.x;
  float s=0.0f, r=0.0f;
  for(int i=t; i<4*CB; i+=256) s += vbuf[i];
  for(int i=t; i<CB;   i+=256) r += rbuf[i];
  __shared__ float rs[256], rr[256];
  rs[t]=s; rr[t]=r; __syncthreads();
  for(int o=128;o>0;o>>=1){ if(t<o){ rs[t]+=rs[t+o]; rr[t]+=rr[t+o]; } __syncthreads(); }
  if(t==0){
    float loss_s = rs[0];
    float loss_r = rr[0]/(float)CB;
    out[0] = loss_r + LAMBDA1*loss_s;
    out[1] = loss_r;
    out[2] = loss_s;
  }
}

// ---------------- launch ----------------
extern "C" void kernel_launch(void* const* d_in, const int* in_sizes, int n_in,
                              void* d_out, int out_size, void* d_ws, size_t ws_size,
                              hipStream_t stream){
  const float* E_u_0   = (const float*)d_in[0];
  const float* E_i_0   = (const float*)d_in[1];
  const float* W_s     = (const float*)d_in[2];
  const float* u_mul_s = (const float*)d_in[3];
  const float* v_mul_s = (const float*)d_in[4];
  const float* ut      = (const float*)d_in[5];
  const float* vt      = (const float*)d_in[6];
  const float* adj_vals= (const float*)d_in[7];
  const int*   adj_rows= (const int*)d_in[8];
  const int*   adj_cols= (const int*)d_in[9];
  const int*   uids    = (const int*)d_in[10];
  const int*   iids    = (const int*)d_in[11];
  const int*   pos_ids = (const int*)d_in[12];
  const int*   neg_ids = (const int*)d_in[13];
  float* out = (float*)d_out;

  float* ws = (float*)d_ws;
  size_t off = 0;
  auto alloc = [&](size_t n){ float* p = ws + off; off += (n+3)&~(size_t)3; return p; };
  ushortT* Eu0b = (ushortT*)alloc((size_t)CNU*CD/2);
  ushortT* Ei0b = (ushortT*)alloc((size_t)CNI*CD/2);
  ushortT* EuA  = (ushortT*)alloc((size_t)CNU*CD/2);
  ushortT* EuB  = (ushortT*)alloc((size_t)CNU*CD/2);
  ushortT* EiA  = (ushortT*)alloc((size_t)CNI*CD/2);
  ushortT* EiB  = (ushortT*)alloc((size_t)CNI*CD/2);
  float* Tbuf = alloc(2*2*CQ*128);          // [layer][side][640]
  float* negb = alloc(4*CB);                // adjacent to Tbuf -> single memset
  ushortT* gnnb = (ushortT*)alloc(4*(size_t)CB*CD/2);
  ushortT* hypb = (ushortT*)alloc(4*(size_t)CB*CD/2);
  float* usum = alloc((size_t)CB*CD);
  float* iposb= alloc((size_t)CB*CD);
  float* inegb= alloc((size_t)CB*CD);
  float* vbuf = alloc(4*CB);
  float* rbuf = alloc(CB);
  int* bcnt_u = (int*)alloc((size_t)NBU*NXCD*16);
  int* bcnt_i = (int*)alloc((size_t)NBI*NXCD*16);   // adjacent to bcnt_u
  int2* bin_u = (int2*)alloc((size_t)NBU*NXCD*SEGCAP_U*2);
  int2* bin_i = (int2*)alloc((size_t)NBI*NXCD*SEGCAP_I*2);
  int* cnt_u = (int*)alloc(CNU);
  int* cnt_i = (int*)alloc(CNI);
  uint32_t* pad_u = (uint32_t*)alloc((size_t)CNU*CAP_R);
  uint32_t* pad_i = (uint32_t*)alloc((size_t)CNI*CAP_C);

  uint32_t rk0 = 0u, rk1 = 42u;
  uint32_t kd[CL][2][2];
  uint32_t km[4][2];
  for(int l=0;l<CL;l++){
    uint32_t o[6]; split3(rk0,rk1,o);
    kd[l][0][0]=o[0]; kd[l][0][1]=o[1];
    kd[l][1][0]=o[2]; kd[l][1][1]=o[3];
    rk0=o[4]; rk1=o[5];
  }
  for(int l=0;l<CL;l++){
    uint32_t o[6]; split3(rk0,rk1,o);
    km[l*2+0][0]=o[0]; km[l*2+0][1]=o[1];
    km[l*2+1][0]=o[2]; km[l*2+1][1]=o[3];
    rk0=o[4]; rk1=o[5];
  }

  // two fused memsets (adjacent allocations)
  hipMemsetAsync(bcnt_u, 0, ((size_t)NBU+NBI)*NXCD*16*sizeof(int), stream);
  hipMemsetAsync(Tbuf, 0, (2*2*CQ*128 + 4*CB)*sizeof(float), stream);

  // D1: binfill || cvt || gacc-init
  k_setup<<<NBF+NCVT+NGA,256,0,stream>>>(adj_rows, adj_cols, adj_vals,
      bcnt_u, bcnt_i, bin_u, bin_i,
      E_u_0, E_i_0, Eu0b, Ei0b,
      uids, pos_ids, neg_ids, usum, iposb, inegb,
      kd[0][0][0],kd[0][0][1], kd[1][0][0],kd[1][0][1],
      kd[0][1][0],kd[0][1][1], kd[1][1][0],kd[1][1][1]);

  // D2: bucket build
  k_build<<<NBU+NBI,256,0,stream>>>(bcnt_u, bin_u, bcnt_i, bin_i,
      cnt_u, pad_u, cnt_i, pad_i);

  const ushortT* Eu_cur = Eu0b;
  const ushortT* Ei_cur = Ei0b;
  ushortT* Eu_next_bufs[2] = {EuA, EuB};
  ushortT* Ei_next_bufs[2] = {EiA, EiB};

  for(int l=0;l<CL;l++){
    ushortT* Eu_next = Eu_next_bufs[l];
    ushortT* Ei_next = Ei_next_bufs[l];

    // spmm (occupancy-critical, standalone)
    k_spmm<<<NSPMM,256,0,stream>>>(
        cnt_u, pad_u, cnt_i, pad_i,
        Eu_cur, Ei_cur, Eu_next, Ei_next, l);

    // low-rank projection (standalone)
    k_vtE2<<<NCH,256,0,stream>>>(vt, ut, Ei_cur, Eu_cur, Tbuf, l);

    // hyper | gnn | gacc
    const float* Wl = W_s + (size_t)l*CD*CD;
    k_sampled<<<7*CB,128,0,stream>>>(
        uids, iids, pos_ids, neg_ids, u_mul_s, v_mul_s, Tbuf, Wl,
        Eu_next, Eu_cur, Ei_next, Ei_cur,
        hypb + (size_t)(l*2+0)*CB*CD, hypb + (size_t)(l*2+1)*CB*CD,
        gnnb + (size_t)(l*2+0)*CB*CD, gnnb + (size_t)(l*2+1)*CB*CD,
        usum, iposb, inegb, l);

    Eu_cur = Eu_next; Ei_cur = Ei_next;
  }

  // MFMA NCE
  dim3 gnce(CB/256, CB/512, 4);
  k_nce_mfma<<<gnce,256,0,stream>>>(gnnb, hypb, negb);

  // loss || bpr
  k_tail<<<4*CB/4 + CB/4,256,0,stream>>>(gnnb, hypb, negb,
      usum, iposb, inegb, vbuf, rbuf,
      km[0][0],km[0][1], km[1][0],km[1][1], km[2][0],km[2][1], km[3][0],km[3][1]);

  // final reduce
  k_final<<<1,256,0,stream>>>(vbuf, rbuf, out);
}